// Round 4
// baseline (1454.234 us; speedup 1.0000x reference)
//
#include <hip/hip_runtime.h>
#include <math.h>

#define NN 4096
#define EE 65536
#define H 128
#define NF 4
#define MNODE 8
#define MEDGE 4
#define NT 2

// ---------------- CSR build ----------------
__global__ void k_count(const int* __restrict__ dst, int* __restrict__ cnt) {
  int e = blockIdx.x * 256 + threadIdx.x;
  if (e < EE) atomicAdd(&cnt[dst[e]], 1);
}

__global__ void k_scan(const int* __restrict__ cnt, int* __restrict__ rp) {
  __shared__ int sh[1024];
  int t = threadIdx.x;
  int v0 = cnt[4*t], v1 = cnt[4*t+1], v2 = cnt[4*t+2], v3 = cnt[4*t+3];
  int p1 = v0, p2 = v0 + v1, p3 = p2 + v2, tot = p3 + v3;
  sh[t] = tot; __syncthreads();
  for (int off = 1; off < 1024; off <<= 1) {
    int add = (t >= off) ? sh[t-off] : 0;
    __syncthreads();
    sh[t] += add;
    __syncthreads();
  }
  int base = sh[t] - tot;
  rp[4*t] = base; rp[4*t+1] = base + p1; rp[4*t+2] = base + p2; rp[4*t+3] = base + p3;
  if (t == 1023) rp[NN] = sh[t];
}

__global__ void k_fill(const int* __restrict__ ei, int* __restrict__ cursor, int* __restrict__ cols) {
  int e = blockIdx.x * 256 + threadIdx.x;
  if (e < EE) {
    int d = ei[EE + e], s = ei[e];
    int pos = atomicAdd(&cursor[d], 1);
    cols[pos] = s;
  }
}

__global__ void k_dinv0(const int* __restrict__ cnt, float* __restrict__ d2, float* __restrict__ d1) {
  int i = blockIdx.x * 256 + threadIdx.x;
  if (i < NN) {
    float c = (float)cnt[i];
    d2[i] = 1.f / sqrtf(c + 2.f);
    d1[i] = 1.f / sqrtf(c + 1.f);
  }
}

__global__ void k_pwnorm(const float* __restrict__ pw, float* __restrict__ pwn) {
  int l = blockIdx.x, t = threadIdx.x; // 64 threads
  float a = pw[l*H + t], b = pw[l*H + 64 + t];
  float s = a*a + b*b;
  for (int off = 32; off > 0; off >>= 1) s += __shfl_down(s, off);
  if (t == 0) pwn[l] = sqrtf(s);
}

__global__ void k_segS(const int* __restrict__ dst, const float* __restrict__ me, float* __restrict__ S) {
  int e = blockIdx.x * 256 + threadIdx.x;
  if (e < EE) {
    int d = dst[e];
#pragma unroll
    for (int m = 0; m < MEDGE; m++) atomicAdd(&S[d*MEDGE + m], me[e*MEDGE + m]);
  }
}

// ---------------- edge-MLP projections: P = na@Wm[0:140], Q = na@Wm[140:280]
__global__ void k_mmPQ(const float* __restrict__ F, const float* __restrict__ mn,
                       const float* __restrict__ h, const float* __restrict__ Wm,
                       float* __restrict__ P, float* __restrict__ Q) {
  constexpr int R = 8;
  int row0 = blockIdx.x * R;
  int t = threadIdx.x; // 128
  float accP[R] = {}, accQ[R] = {};
#pragma unroll
  for (int kk = 0; kk < NF; kk++) {
    float b1 = Wm[kk*H + t], b2 = Wm[(140 + kk)*H + t];
#pragma unroll
    for (int r = 0; r < R; r++) {
      float a = F[(row0 + r)*NF + kk];
      accP[r] += a*b1; accQ[r] += a*b2;
    }
  }
#pragma unroll
  for (int kk = 0; kk < MNODE; kk++) {
    float b1 = Wm[(NF + kk)*H + t], b2 = Wm[(140 + NF + kk)*H + t];
#pragma unroll
    for (int r = 0; r < R; r++) {
      float a = mn[(row0 + r)*MNODE + kk];
      accP[r] += a*b1; accQ[r] += a*b2;
    }
  }
#pragma unroll 2
  for (int kk = 0; kk < H; kk++) {
    float b1 = Wm[(12 + kk)*H + t], b2 = Wm[(152 + kk)*H + t];
#pragma unroll
    for (int r = 0; r < R; r++) {
      float a = h[(size_t)(row0 + r)*H + kk];
      accP[r] += a*b1; accQ[r] += a*b2;
    }
  }
#pragma unroll
  for (int r = 0; r < R; r++) {
    P[(size_t)(row0 + r)*H + t] = accP[r];
    Q[(size_t)(row0 + r)*H + t] = accQ[r];
  }
}

// h1 = relu(cnt_i*(P_i+bm) + (A@Q)_i + S_i@WmB); fused: ts = dinv2_i * (h1_row @ Wd0)
__global__ void k_h1mm(const float* __restrict__ Q, const int* __restrict__ rp,
                       const int* __restrict__ cols, const float* __restrict__ P,
                       const float* __restrict__ bm, const float* __restrict__ S,
                       const float* __restrict__ WmB, const int* __restrict__ cnt,
                       const float* __restrict__ Wd0, const float* __restrict__ dinv2,
                       float* __restrict__ h1, float* __restrict__ ts) {
  __shared__ float row[128];
  int i = blockIdx.x, t = threadIdx.x;
  float acc = 0.f;
  int beg = rp[i], end = rp[i+1];
  for (int e = beg; e < end; e++) acc += Q[(size_t)cols[e]*H + t];
  float v = (float)cnt[i] * (P[(size_t)i*H + t] + bm[t]) + acc;
#pragma unroll
  for (int m = 0; m < MEDGE; m++) v += S[i*MEDGE + m] * WmB[m*H + t];
  v = fmaxf(v, 0.f);
  h1[(size_t)i*H + t] = v;
  row[t] = v;
  __syncthreads();
  float o = 0.f;
#pragma unroll 4
  for (int kk = 0; kk < H; kk++) o += row[kk] * Wd0[kk*H + t];
  ts[(size_t)i*H + t] = o * dinv2[i];
}

// GCN0 spmm epilogue + level-0 score/key epilogue
__global__ void k_gcn0(const float* __restrict__ ts, const int* __restrict__ rp,
                       const int* __restrict__ cols, const float* __restrict__ dinv,
                       const float* __restrict__ bias, const float* __restrict__ pw,
                       const float* __restrict__ pwn, float* __restrict__ out,
                       float* __restrict__ score, unsigned long long* __restrict__ keys) {
  __shared__ float sred[128];
  int i = blockIdx.x, t = threadIdx.x;
  float acc = 0.f;
  int beg = rp[i], end = rp[i+1];
  for (int e = beg; e < end; e++) acc += ts[(size_t)cols[e]*H + t];
  float v = dinv[i] * (acc + 2.f * ts[(size_t)i*H + t]) + bias[t];
  v = fmaxf(v, 0.f);
  out[(size_t)i*H + t] = v;
  sred[t] = v * pw[t];
  __syncthreads();
  for (int off = 64; off > 0; off >>= 1) { if (t < off) sred[t] += sred[t+off]; __syncthreads(); }
  if (t == 0) {
    float sc = tanhf(sred[0] / pwn[0]);
    score[i] = sc;
    unsigned u = __float_as_uint(sc + 0.0f);
    u ^= ((unsigned)((int)u >> 31)) | 0x80000000u;
    keys[i] = ((unsigned long long)u << 12) | (unsigned)(4095 - i);
  }
}

// row-blocked 128x128 GEMM with optional perm/sv (pooled-x) and dinv scaling
__global__ void k_mm_multi(const float* __restrict__ A, const float* __restrict__ B,
                           float* __restrict__ C, int nrows, const float* __restrict__ dinv,
                           const int* __restrict__ perm, const float* __restrict__ sv) {
  constexpr int R = 8;
  int row0 = blockIdx.x * R;
  int t = threadIdx.x; // 128
  float acc[R] = {};
  int rows[R];
#pragma unroll
  for (int r = 0; r < R; r++) {
    int row = row0 + r;
    rows[r] = (row < nrows) ? (perm ? perm[row] : row) : 0;
  }
#pragma unroll 4
  for (int kk = 0; kk < H; kk++) {
    float b = B[kk*H + t];
#pragma unroll
    for (int r = 0; r < R; r++) acc[r] += A[(size_t)rows[r]*H + kk] * b;
  }
#pragma unroll
  for (int r = 0; r < R; r++) {
    int row = row0 + r;
    if (row < nrows) {
      float scale = (dinv ? dinv[row] : 1.f) * (sv ? sv[row] : 1.f);
      C[(size_t)row*H + t] = acc[r] * scale;
    }
  }
}

// exact top-k rank (jax.lax.top_k semantics). One pass, no atomics:
// each thread streams all keys through LDS tiles, counts greater keys, scatters.
__global__ void k_toprank(const unsigned long long* __restrict__ keys,
                          const float* __restrict__ score, int n, int k,
                          int* __restrict__ perm, float* __restrict__ sv,
                          int* __restrict__ rank) {
  __shared__ unsigned long long kt[512];
  int t = threadIdx.x;
  int i = blockIdx.x * 256 + t;
  unsigned long long ki = (i < n) ? keys[i] : 0ULL;
  int r = 0;
  for (int j0 = 0; j0 < n; j0 += 512) {
    int jn = n - j0; if (jn > 512) jn = 512;
    __syncthreads();
    for (int j = t; j < 512; j += 256) kt[j] = (j < jn) ? keys[j0 + j] : 0ULL;
    __syncthreads();
    const ulonglong2* k2 = (const ulonglong2*)kt;
#pragma unroll 8
    for (int j = 0; j < 256; j++) {
      ulonglong2 v = k2[j];
      r += (v.x > ki) ? 1 : 0;
      r += (v.y > ki) ? 1 : 0;
    }
  }
  if (i < n) {
    rank[i] = r;
    if (r < k) { perm[r] = i; sv[r] = score[i]; }
  }
}

// A_820[r,c] = (A1@A1)[perm_r, perm_c], diag zeroed; A1 = offdiag(A0)+I via CSR.
// Fused: dv[r] = rsqrt(rowsum + 2).
__global__ void k_a820(const int* __restrict__ rp, const int* __restrict__ cols,
                       const int* __restrict__ perm, float* __restrict__ A820,
                       float* __restrict__ dv) {
  __shared__ float acc[NN];
  __shared__ float red[256];
  int r = blockIdx.x, t = threadIdx.x;
  for (int i = t; i < NN; i += 256) acc[i] = 0.f;
  __syncthreads();
  int pi = perm[r];
  int beg = rp[pi], end = rp[pi+1];
  for (int e = beg + t; e < end; e += 256) { int c = cols[e]; if (c != pi) atomicAdd(&acc[c], 1.f); }
  if (t == 0) atomicAdd(&acc[pi], 1.f);
  for (int e0 = beg; e0 < end; e0++) {
    int c = cols[e0];
    if (c == pi) continue;
    int b2 = rp[c], e2 = rp[c+1];
    for (int e = b2 + t; e < e2; e += 256) { int c2 = cols[e]; if (c2 != c) atomicAdd(&acc[c2], 1.f); }
    if (t == 0) atomicAdd(&acc[c], 1.f);
  }
  __syncthreads();
  float psum = 0.f;
  for (int cc = t; cc < 820; cc += 256) {
    float v = (cc == r) ? 0.f : acc[perm[cc]];
    A820[(size_t)r*820 + cc] = v;
    psum += v;
  }
  red[t] = psum; __syncthreads();
  for (int off = 128; off > 0; off >>= 1) { if (t < off) red[t] += red[t+off]; __syncthreads(); }
  if (t == 0) dv[r] = 1.f / sqrtf(red[0] + 2.f);
}

// dense augment+pool, row-major access: compact nonzeros of A[pr,:] to LDS, then
// each thread owns one output column c (gathers WITHIN rows: uniform base + perm[c]).
// out[r,c] = sum_kk A[pr,kk]*A[kk,pc] + 2*A[pr,pc] (r!=c), 0 diag. Values are exact
// small ints in fp32 -> reassociation-safe. Fused dv[r] = rsqrt(rowsum+2).
__global__ void k_augpool(const float* __restrict__ A, int n, const int* __restrict__ perm,
                          int knext, float* __restrict__ out, float* __restrict__ dv) {
  __shared__ float rowv[832];
  __shared__ int rowi[832];
  __shared__ int pcs[192];
  __shared__ int nnz_sh;
  __shared__ float red[256];
  int r = blockIdx.x, t = threadIdx.x;
  if (t == 0) nnz_sh = 0;
  __syncthreads();
  int pr = perm[r];
  for (int c = t; c < knext; c += 256) pcs[c] = perm[c];
  for (int i = t; i < n; i += 256) {
    float v = A[(size_t)pr*n + i];
    if (v != 0.f) { int pos = atomicAdd(&nnz_sh, 1); rowv[pos] = v; rowi[pos] = i; }
  }
  __syncthreads();
  int nnz = nnz_sh;
  int pc = (t < knext) ? pcs[t] : 0;
  float acc = 0.f;
#pragma unroll 4
  for (int e = 0; e < nnz; e++) acc += rowv[e] * A[(size_t)rowi[e]*n + pc];
  float v = 0.f;
  if (t < knext) {
    v = (t == r) ? 0.f : (acc + 2.f * A[(size_t)pr*n + pc]);
    out[(size_t)r*knext + t] = v;
  }
  red[t] = v; __syncthreads();
  for (int off = 128; off > 0; off >>= 1) { if (t < off) red[t] += red[t+off]; __syncthreads(); }
  if (t == 0) dv[r] = 1.f / sqrtf(red[0] + 2.f);
}

// dense GCN apply + optional score epilogue (lvl>=0)
__global__ void k_dense_gcn(const float* __restrict__ A, int n, const float* __restrict__ ts,
                            const float* __restrict__ dinv, const float* __restrict__ bias,
                            int relu, float* __restrict__ out,
                            int lvl, const float* __restrict__ pw, const float* __restrict__ pwn,
                            float* __restrict__ score, unsigned long long* __restrict__ keys) {
  __shared__ float arow[128];
  int i = blockIdx.x, t = threadIdx.x;
  float acc = 0.f;
  for (int k0 = 0; k0 < n; k0 += H) {
    int m = (n - k0 < H) ? (n - k0) : H;
    if (t < m) arow[t] = A[(size_t)i*n + k0 + t];
    __syncthreads();
    for (int kk = 0; kk < m; kk++) {
      float a = arow[kk];
      if (a != 0.f) acc += a * ts[(size_t)(k0 + kk)*H + t];
    }
    __syncthreads();
  }
  float v = dinv[i] * (acc + 2.f * ts[(size_t)i*H + t]) + bias[t];
  if (relu) v = fmaxf(v, 0.f);
  out[(size_t)i*H + t] = v;
  if (lvl >= 0) {
    __syncthreads();
    arow[t] = v * pw[t];
    __syncthreads();
    for (int off = 64; off > 0; off >>= 1) { if (t < off) arow[t] += arow[t+off]; __syncthreads(); }
    if (t == 0) {
      float sc = tanhf(arow[0] / pwn[lvl]);
      score[i] = sc;
      unsigned u = __float_as_uint(sc + 0.0f);
      u ^= ((unsigned)((int)u >> 31)) | 0x80000000u;
      keys[i] = ((unsigned long long)u << 12) | (unsigned)(4095 - i);
    }
  }
}

// up-path fused: ts[row] = dinv_row * ((res[row] + up[row]) @ B), up via rank scatter
__global__ void k_up_mm(const float* __restrict__ res, const int* __restrict__ rank, int k,
                        const float* __restrict__ xc, const float* __restrict__ B,
                        const float* __restrict__ dinv, float* __restrict__ ts, int nrows) {
  constexpr int R = 8;
  int row0 = blockIdx.x * R;
  int t = threadIdx.x; // 128
  float acc[R] = {};
  const float* ap[R];
  float sc[R];
  int rowc[R];
#pragma unroll
  for (int r = 0; r < R; r++) {
    int row = row0 + r;
    rowc[r] = (row < nrows) ? row : (nrows - 1);
    int rnk = rank[rowc[r]];
    sc[r] = (rnk < k) ? 1.f : 0.f;
    ap[r] = xc + (size_t)((rnk < k) ? rnk : 0) * H;
  }
#pragma unroll 2
  for (int kk = 0; kk < H; kk++) {
    float b = B[kk*H + t];
#pragma unroll
    for (int r = 0; r < R; r++) {
      float a = res[(size_t)rowc[r]*H + kk] + sc[r] * ap[r][kk];
      acc[r] += a * b;
    }
  }
#pragma unroll
  for (int r = 0; r < R; r++) {
    int row = row0 + r;
    if (row < nrows) ts[(size_t)row*H + t] = acc[r] * dinv[row];
  }
}

// final up SpMM (fill=2, no relu) -> hbuf (next-step h), fused outproj:
// ts2[i,0:4] = dinv1_i * (cat([h1_i, relu(h2_i)]) @ Wout)
__global__ void k_spmm_out(const float* __restrict__ ts, const int* __restrict__ rp,
                           const int* __restrict__ cols, const float* __restrict__ dinv2,
                           const float* __restrict__ bias, const float* __restrict__ h1,
                           const float* __restrict__ Wout, const float* __restrict__ dinv1,
                           float* __restrict__ hbuf, float* __restrict__ ts2) {
  __shared__ float wred[2][4];
  int i = blockIdx.x, t = threadIdx.x; // 128
  float acc = 0.f;
  int beg = rp[i], end = rp[i+1];
  for (int e = beg; e < end; e++) acc += ts[(size_t)cols[e]*H + t];
  float h2 = dinv2[i] * (acc + 2.f * ts[(size_t)i*H + t]) + bias[t];
  hbuf[(size_t)i*H + t] = h2;
  float h1v = h1[(size_t)i*H + t];
  float h2r = fmaxf(h2, 0.f);
  float p0 = h1v*Wout[t*4+0] + h2r*Wout[(128+t)*4+0];
  float p1 = h1v*Wout[t*4+1] + h2r*Wout[(128+t)*4+1];
  float p2 = h1v*Wout[t*4+2] + h2r*Wout[(128+t)*4+2];
  float p3 = h1v*Wout[t*4+3] + h2r*Wout[(128+t)*4+3];
#pragma unroll
  for (int off = 32; off > 0; off >>= 1) {
    p0 += __shfl_down(p0, off); p1 += __shfl_down(p1, off);
    p2 += __shfl_down(p2, off); p3 += __shfl_down(p3, off);
  }
  int w = t >> 6, lane = t & 63;
  if (lane == 0) { wred[w][0] = p0; wred[w][1] = p1; wred[w][2] = p2; wred[w][3] = p3; }
  __syncthreads();
  if (t == 0) {
    float d = dinv1[i];
    ts2[i*4+0] = d*(wred[0][0] + wred[1][0]);
    ts2[i*4+1] = d*(wred[0][1] + wred[1][1]);
    ts2[i*4+2] = d*(wred[0][2] + wred[1][2]);
    ts2[i*4+3] = d*(wred[0][3] + wred[1][3]);
  }
}

__global__ void k_gcn_out(const float* __restrict__ ts2, const int* __restrict__ rp,
                          const int* __restrict__ cols, const float* __restrict__ dinv1,
                          const float* __restrict__ bout, float* __restrict__ Fcur,
                          float* __restrict__ dout, int tstep) {
  int i = blockIdx.x, t = threadIdx.x; // 64 threads
  int f = t & 3;
  float acc = 0.f;
  int beg = rp[i], end = rp[i+1];
  for (int e = beg + (t >> 2); e < end; e += 16) acc += ts2[cols[e]*4 + f];
  for (int off = 32; off >= 4; off >>= 1) acc += __shfl_down(acc, off);
  if (t < 4) {
    float v = dinv1[i] * (acc + ts2[i*4 + f]) + bout[f];
    Fcur[i*4 + f] = v;
    dout[i*(NT*NF) + tstep*NF + f] = v;
  }
}

extern "C" void kernel_launch(void* const* d_in, const int* in_sizes, int n_in,
                              void* d_out, int out_size, void* d_ws, size_t ws_size,
                              hipStream_t stream) {
  const float* F0        = (const float*)d_in[0];
  const float* mesh_node = (const float*)d_in[1];
  const float* mesh_edge = (const float*)d_in[2];
  const float* Wm        = (const float*)d_in[3];
  const float* bm        = (const float*)d_in[4];
  const float* Wd0       = (const float*)d_in[5];
  const float* bd0       = (const float*)d_in[6];
  const float* Wd        = (const float*)d_in[7];
  const float* bd        = (const float*)d_in[8];
  const float* pool_w    = (const float*)d_in[9];
  const float* Wu        = (const float*)d_in[10];
  const float* bu        = (const float*)d_in[11];
  const float* Wout      = (const float*)d_in[12];
  const float* bout      = (const float*)d_in[13];
  const int*   ei        = (const int*)d_in[14];
  float* out = (float*)d_out;

  char* p = (char*)d_ws;
  auto carve = [&](size_t bytes) -> char* {
    char* r = p;
    p += (bytes + 255) & ~(size_t)255;
    return r;
  };
  int*   cnt    = (int*)carve((size_t)NN*4);
  int*   rp     = (int*)carve((size_t)(NN+1)*4);
  int*   cursor = (int*)carve((size_t)NN*4);
  int*   cols   = (int*)carve((size_t)EE*4);
  int*   permb  = (int*)carve((size_t)5*832*4);
  float* svb    = (float*)carve((size_t)5*832*4);
  int*   rankb  = (int*)carve((size_t)5*NN*4);
  unsigned long long* keys = (unsigned long long*)carve((size_t)NN*8);
  float* dinv2  = (float*)carve((size_t)NN*4);
  float* dinv1  = (float*)carve((size_t)NN*4);
  float* pwn    = (float*)carve(8*4);
  float* S      = (float*)carve((size_t)NN*MEDGE*4);
  float* P      = (float*)carve((size_t)NN*H*4);
  float* Q      = (float*)carve((size_t)NN*H*4);
  float* h1     = (float*)carve((size_t)NN*H*4);
  float* hbuf   = (float*)carve((size_t)NN*H*4);
  float* tsb    = (float*)carve((size_t)NN*H*4);
  float* x0     = (float*)carve((size_t)NN*H*4);
  float* x1     = (float*)carve((size_t)820*H*4);
  float* x2     = (float*)carve((size_t)164*H*4);
  float* x3     = (float*)carve((size_t)33*H*4);
  float* x4     = (float*)carve((size_t)7*H*4);
  float* xcur   = (float*)carve((size_t)820*H*4);
  float* score  = (float*)carve((size_t)NN*4);
  float* A820   = (float*)carve((size_t)820*820*4);
  float* A164   = (float*)carve((size_t)164*164*4);
  float* A33    = (float*)carve((size_t)33*33*4);
  float* A7     = (float*)carve((size_t)7*7*4);
  float* A2b    = (float*)carve((size_t)2*2*4);
  float* dv820  = (float*)carve(820*4);
  float* dv164  = (float*)carve(164*4);
  float* dv33   = (float*)carve(33*4);
  float* dv7    = (float*)carve(7*4);
  float* dv2    = (float*)carve(2*4);
  float* ts2    = (float*)carve((size_t)NN*NF*4);
  float* Fcur   = (float*)carve((size_t)NN*NF*4);

  const int KLh[5]  = {820, 164, 33, 7, 2};
  const int szs[5]  = {4096, 820, 164, 33, 7};
  float* Adense[5] = {A820, A164, A33, A7, A2b};
  float* dvl[5]    = {dv820, dv164, dv33, dv7, dv2};
  float* xsv[5]    = {x0, x1, x2, x3, x4};
  int* perml[5]; float* svl[5]; int* rankl[5];
  for (int l = 0; l < 5; l++) {
    perml[l] = permb + l*832; svl[l] = svb + l*832; rankl[l] = rankb + l*NN;
  }

  // ---- setup (once per launch) ----
  hipMemsetAsync(cnt, 0, (size_t)NN*4, stream);
  hipMemsetAsync(S, 0, (size_t)NN*MEDGE*4, stream);
  hipMemsetAsync(hbuf, 0, (size_t)NN*H*4, stream);
  k_count<<<EE/256, 256, 0, stream>>>(ei + EE, cnt);
  k_scan<<<1, 1024, 0, stream>>>(cnt, rp);
  hipMemcpyAsync(cursor, rp, (size_t)NN*4, hipMemcpyDeviceToDevice, stream);
  k_fill<<<EE/256, 256, 0, stream>>>(ei, cursor, cols);
  k_dinv0<<<NN/256, 256, 0, stream>>>(cnt, dinv2, dinv1);
  k_pwnorm<<<5, 64, 0, stream>>>(pool_w, pwn);
  k_segS<<<EE/256, 256, 0, stream>>>(ei + EE, mesh_edge, S);
  hipMemcpyAsync(Fcur, F0, (size_t)NN*NF*4, hipMemcpyDeviceToDevice, stream);

  for (int step = 0; step < NT; step++) {
    // edge MLP (factored) -> h1; fused Wd0 projection
    k_mmPQ<<<NN/8, 128, 0, stream>>>(Fcur, mesh_node, hbuf, Wm, P, Q);
    k_h1mm<<<NN, 128, 0, stream>>>(Q, rp, cols, P, bm, S, Wm + 280*H, cnt, Wd0, dinv2, h1, tsb);
    // GCN0 (fill=2, relu) + level-0 score
    k_gcn0<<<NN, 128, 0, stream>>>(tsb, rp, cols, dinv2, bd0, pool_w, pwn, x0, score, keys);

    // down path
    for (int i = 0; i < 5; i++) {
      int n_prev = szs[i], k = KLh[i];
      k_toprank<<<(n_prev + 255)/256, 256, 0, stream>>>(keys, score, n_prev, k,
                                                        perml[i], svl[i], rankl[i]);
      if (i == 0) k_a820<<<820, 256, 0, stream>>>(rp, cols, perml[0], Adense[0], dvl[0]);
      else        k_augpool<<<k, 256, 0, stream>>>(Adense[i-1], n_prev, perml[i], k,
                                                   Adense[i], dvl[i]);
      k_mm_multi<<<(k + 7)/8, 128, 0, stream>>>(xsv[i], Wd + i*H*H, tsb, k, dvl[i],
                                                perml[i], svl[i]);
      float* outx = (i < 4) ? xsv[i+1] : xcur;
      int lvl = (i < 4) ? (i + 1) : -1;
      k_dense_gcn<<<k, 128, 0, stream>>>(Adense[i], k, tsb, dvl[i], bd + i*H, 1, outx,
                                         lvl, pool_w + (i+1 < 5 ? (i+1)*H : 0), pwn,
                                         score, keys);
    }

    // up path
    for (int i = 0; i < 5; i++) {
      int j = 4 - i;
      int n = szs[j], kk = KLh[j];
      const float* dv_up = (j > 0) ? dvl[j-1] : dinv2;
      k_up_mm<<<(n + 7)/8, 128, 0, stream>>>(xsv[j], rankl[j], kk, xcur,
                                             Wu + i*H*H, dv_up, tsb, n);
      if (j > 0) {
        k_dense_gcn<<<n, 128, 0, stream>>>(Adense[j-1], n, tsb, dvl[j-1], bu + i*H,
                                           (i < 4) ? 1 : 0, xcur,
                                           -1, pool_w, pwn, score, keys);
      } else {
        k_spmm_out<<<NN, 128, 0, stream>>>(tsb, rp, cols, dinv2, bu + i*H, h1,
                                           Wout, dinv1, hbuf, ts2);
      }
    }

    k_gcn_out<<<NN, 64, 0, stream>>>(ts2, rp, cols, dinv1, bout, Fcur, out, step);
  }
}